// Round 8
// baseline (122.121 us; speedup 1.0000x reference)
//
#include <hip/hip_runtime.h>

// BilateralFilter3D 3x3x3, replicate pad, sigma_d=120, sigma_r=1.2
// (B,1,128,192,192) fp32.
//
// Round 8: TLP restoration. Cross-round evidence: busy-time pinned ~24us
// (math floor, quad poly) for r5-r7 while wall tracks occupancy inversely
// (r1 occ73%->busy100%; r7 occ12.6%->busy50%). The z-march made few fat
// convoying blocks; effective latency is L3-class (~600cyc) and 1-2
// waves/SIMD can't hide it. Fix = r3's flat shape (thread = 4 voxels, one
// z per block-row, 12288 blocks = 48 blocks/CU queued) + the sched_barrier
// phase split r3 was missing (its loads got re-serialized into 9 load->use
// groups) + quadratic poly. Per wave: 27 loads batched (MLP=27,
// progressive vmcnt drain), ~1400cyc compute, ~5 waves/SIMD resident.

typedef float f4 __attribute__((ext_vector_type(4)));

constexpr int Dd = 128;
constexpr int Hh = 192;
constexpr int Ww = 192;

// quadratic minimax for exp(-t/(2*1.2^2)), t in [0,1]; spatial weights
// (dev <= 1.05e-4 from 1) folded out. Output shift < 5e-4 vs 1.69e-2 thr.
constexpr float A0 = 0.9998131f;
constexpr float A1 = -0.3437852f;
constexpr float A2 = 0.0508019f;

__device__ __forceinline__ f4 splat4(float v) { return (f4){v, v, v, v}; }

struct Row { f4 m; float lf, rf; };   // 4-voxel span + clamped edge scalars

__global__ __launch_bounds__(192)
void bilateral3d_v8(const float* __restrict__ vol, float* __restrict__ out)
{
    const int t  = threadIdx.x;              // 0..47
    const int ty = threadIdx.y;              // 0..3
    const int h  = (blockIdx.x << 2) + ty;   // 0..191
    const int z  = blockIdx.y;               // 0..127
    const int b  = blockIdx.z;

    const size_t plane = (size_t)Hh * Ww;
    const float* __restrict__ base = vol + (size_t)b * Dd * plane;

    const int x0 = t << 2;
    const int lx = (x0 > 0) ? x0 - 1 : 0;           // replicate via address clamp
    const int rx = (x0 + 4 < Ww) ? x0 + 4 : Ww - 1;
    const int yy[3] = { (h > 0) ? h - 1 : 0, h, (h < Hh - 1) ? h + 1 : Hh - 1 };
    const int zz[3] = { (z > 0) ? z - 1 : 0, z, (z < Dd - 1) ? z + 1 : Dd - 1 };

    // ---- phase 1: all 27 loads, batched (MLP=27) ----
    Row P[3][3];
#pragma unroll
    for (int p = 0; p < 3; ++p) {
        const float* __restrict__ zb = base + (size_t)zz[p] * plane;
#pragma unroll
        for (int r = 0; r < 3; ++r) {
            const float* __restrict__ row = zb + (size_t)yy[r] * Ww;
            P[p][r].m  = *(const f4*)(row + x0);
            P[p][r].lf = row[lx];
            P[p][r].rf = row[rx];
        }
    }
    __builtin_amdgcn_sched_barrier(0);   // loads may not sink below this

    // ---- phase 2: compute ----
    const f4 c = P[1][1].m;
    f4 num = splat4(0.0f);
    f4 den = splat4(0.0f);

#define ACC(nv)                                                               \
    do {                                                                      \
        f4 _df = (nv) - c;                                                    \
        f4 _t  = _df * _df;                                                   \
        f4 _w  = __builtin_elementwise_fma(_t,                                \
                   __builtin_elementwise_fma(_t, splat4(A2), splat4(A1)),     \
                   splat4(A0));                                               \
        num = __builtin_elementwise_fma(_w, (nv), num);                       \
        den = den + _w;                                                       \
    } while (0)

#pragma unroll
    for (int p = 0; p < 3; ++p) {
#pragma unroll
        for (int r = 0; r < 3; ++r) {
            const f4 M  = P[p][r].m;
            const f4 nL = (f4){P[p][r].lf, M.x, M.y, M.z};   // dx=-1
            const f4 nR = (f4){M.y, M.z, M.w, P[p][r].rf};   // dx=+1
            ACC(nL);
            ACC(M);     // center (p==1,r==1) const-folds: w == A0
            ACC(nR);
        }
    }
#undef ACC

    // den >= ~19: reference clip(1e-8) is a no-op; fast rcp ~1ulp
    f4 res;
    res.x = num.x * __builtin_amdgcn_rcpf(den.x);
    res.y = num.y * __builtin_amdgcn_rcpf(den.y);
    res.z = num.z * __builtin_amdgcn_rcpf(den.z);
    res.w = num.w * __builtin_amdgcn_rcpf(den.w);

    float* __restrict__ orow =
        out + (size_t)b * Dd * plane + (size_t)z * plane + (size_t)h * Ww + x0;
    *(f4*)orow = res;
}

extern "C" void kernel_launch(void* const* d_in, const int* in_sizes, int n_in,
                              void* d_out, int out_size, void* d_ws, size_t ws_size,
                              hipStream_t stream)
{
    const float* vol = (const float*)d_in[0];
    float* out       = (float*)d_out;

    const int B = in_sizes[0] / (Dd * Hh * Ww);   // = 2

    dim3 grid(Hh / 4, Dd, B);   // (48, 128, 2) = 12288 blocks
    dim3 block(Ww / 4, 4, 1);   // 48 x 4 = 192 threads = 3 waves
    bilateral3d_v8<<<grid, block, 0, stream>>>(vol, out);
}

// Round 9
// 113.428 us; speedup vs baseline: 1.0766x; 1.0766x over previous
//
#include <hip/hip_runtime.h>

// BilateralFilter3D 3x3x3, replicate pad, sigma_d=120, sigma_r=1.2
// (B,1,128,192,192) fp32.
//
// Round 9: LDS staging. r8 falsified the TLP theory (occ 42%, VALUBusy 45%):
// the bottleneck is the per-CU shared vector-memory path — 27 redundant
// global loads/thread at ~16 cache-lines each ≈ 26us of TA line-cycles,
// queueing against the ~20us VALU floor (both pipes ~50%). Fix: block =
// 192-wide row x 4 H-rows, z-march; per step stage ONE contiguous 6-row
// slab (1.5 f4/thread, 13x less TA) into double-buffered LDS; neighbors
// read as stride-1 ds_read_b32 (2-way bank = free). Plane state rotates in
// registers; only the new plane is read from LDS (18 b32/step), consumed
// last so ds latency hides under p=0/1 compute. Prefetch->ds_write distance
// = full compute block. W-replicate via LDS halo cells; H/z via uniform
// clamped addresses.

typedef float f4 __attribute__((ext_vector_type(4)));

constexpr int Dd = 128, Hh = 192, Ww = 192;
constexpr int NH = 4;            // output rows per block
constexpr int ZC = 4;            // z-steps per block
constexpr int RS = 200;          // LDS row stride (floats); 800B, 16B-mult
constexpr int SLAB = 6 * RS;     // 1200 floats per slab
constexpr int PLANE = Hh * Ww;

// quadratic minimax for exp(-t/(2*1.2^2)), t in [0,1]; spatial weights
// (dev <= 1.05e-4 from 1) folded out. Output shift < 5e-4 vs 1.69e-2 thr.
constexpr float A0 = 0.9998131f, A1 = -0.3437852f, A2 = 0.0508019f;

__device__ __forceinline__ int clampH(int y) {
    return y < 0 ? 0 : (y > Hh - 1 ? Hh - 1 : y);
}

__global__ __launch_bounds__(192)
void bilateral3d_v9(const float* __restrict__ vol, float* __restrict__ out)
{
    __shared__ float lds[2 * SLAB];          // 9600 B, double-buffered slab

    const int tid = threadIdx.x;             // 0..191 == W column
    const int h0  = blockIdx.x * NH;         // 0,4,...,188
    const int z0  = blockIdx.y * ZC;         // 0,4,...,124
    const int b   = blockIdx.z;

    const float* __restrict__ base  = vol + (size_t)b * Dd * PLANE;
    float* __restrict__       obase = out + (size_t)b * Dd * PLANE;

    // staging roles: item0 = f4 #tid (row r0=tid/48), item1 = f4 #(192+tid)
    // for tid<96 (rows 4,5), halo scalars for tid in [96,108)
    const int r0  = tid / 48;
    const int c0  = (tid % 48) * 4;
    const int gy0 = clampH(h0 - 1 + r0);
    const int gy1 = clampH(h0 + 3 + r0);     // = h0-1 + (4+r0), r0 in {0,1}
    const int rh  = (tid - 96) >> 1;         // valid for tid in [96,108)
    const int gyh = clampH(h0 - 1 + (rh < 0 ? 0 : (rh > 5 ? 5 : rh)));
    const int hx  = (tid & 1) ? Ww - 1 : 0;  // replicate source column

    // compute-side clamped x neighbors (preamble direct loads only)
    const int xm = tid > 0 ? tid - 1 : 0;
    const int xp = tid < Ww - 1 ? tid + 1 : Ww - 1;

    float P0[6][3], P1[6][3], P2[6][3];      // [slab row][L,M,R]

    // ---- preamble: planes z0-1, z0 direct to registers ----
    {
        const float* zp = base + (size_t)(z0 > 0 ? z0 - 1 : 0) * PLANE;
#pragma unroll
        for (int r = 0; r < 6; ++r) {
            const float* row = zp + (size_t)clampH(h0 - 1 + r) * Ww;
            P0[r][0] = row[xm]; P0[r][1] = row[tid]; P0[r][2] = row[xp];
        }
        zp = base + (size_t)z0 * PLANE;
#pragma unroll
        for (int r = 0; r < 6; ++r) {
            const float* row = zp + (size_t)clampH(h0 - 1 + r) * Ww;
            P1[r][0] = row[xm]; P1[r][1] = row[tid]; P1[r][2] = row[xp];
        }
    }
    // stage slab(z0+1) into slot 0
    {
        const int z = (z0 + 1 < Dd) ? z0 + 1 : Dd - 1;
        const float* zp = base + (size_t)z * PLANE;
        f4 a = *(const f4*)(zp + (size_t)gy0 * Ww + c0);
        f4 bb = a; float hv = 0.f;
        if (tid < 96)               bb = *(const f4*)(zp + (size_t)gy1 * Ww + c0);
        if (tid >= 96 && tid < 108) hv = zp[(size_t)gyh * Ww + hx];
        float* sl = &lds[0];
        *(f4*)(sl + r0 * RS + 4 + c0) = a;
        if (tid < 96)               *(f4*)(sl + (4 + r0) * RS + 4 + c0) = bb;
        if (tid >= 96 && tid < 108) sl[rh * RS + ((tid & 1) ? 196 : 3)] = hv;
    }
    __syncthreads();

#pragma unroll
    for (int dz = 0; dz < ZC; ++dz) {
        const int z = z0 + dz;

        // 1. prefetch slab(z+2) into registers (consumed only at step end)
        const int zn = (z + 2 < Dd) ? z + 2 : Dd - 1;
        const float* zp = base + (size_t)zn * PLANE;
        f4 Ga = *(const f4*)(zp + (size_t)gy0 * Ww + c0);
        f4 Gb = Ga; float Gh = 0.f;
        if (tid < 96)               Gb = *(const f4*)(zp + (size_t)gy1 * Ww + c0);
        if (tid >= 96 && tid < 108) Gh = zp[(size_t)gyh * Ww + hx];

        // 2. read plane z+1 rows from LDS slot (dz&1): stride-1 b32, no conflicts
        {
            const float* rsl = &lds[(dz & 1) * SLAB];
#pragma unroll
            for (int r = 0; r < 6; ++r) {
                P2[r][0] = rsl[r * RS + 3 + tid];   // x-1 (halo at idx 3)
                P2[r][1] = rsl[r * RS + 4 + tid];   // x
                P2[r][2] = rsl[r * RS + 5 + tid];   // x+1 (halo at idx 196)
            }
        }

        // 3. compute 4 output rows; p=2 (fresh ds_reads) consumed last
        float num[NH], den[NH];
#pragma unroll
        for (int o = 0; o < NH; ++o) { num[o] = 0.f; den[o] = 0.f; }
        const float cen[NH] = { P1[1][1], P1[2][1], P1[3][1], P1[4][1] };

#pragma unroll
        for (int p = 0; p < 3; ++p) {
#pragma unroll
            for (int r = 0; r < 6; ++r) {
#pragma unroll
                for (int c = 0; c < 3; ++c) {
                    const float n = (p == 0 ? P0 : p == 1 ? P1 : P2)[r][c];
                    const int olo = (r - 2 < 0) ? 0 : r - 2;
                    const int ohi = (r < NH - 1) ? r : NH - 1;
#pragma unroll
                    for (int o = olo; o <= ohi; ++o) {
                        const float df = n - cen[o];
                        const float t  = df * df;
                        const float w  = fmaf(t, fmaf(t, A2, A1), A0);
                        num[o] = fmaf(w, n, num[o]);
                        den[o] += w;
                    }
                }
            }
        }

        // 4. store 4 rows (lane = column: fully coalesced)
        {
            float* orow = obase + (size_t)z * PLANE + (size_t)h0 * Ww + tid;
#pragma unroll
            for (int o = 0; o < NH; ++o)
                orow[(size_t)o * Ww] = num[o] * __builtin_amdgcn_rcpf(den[o]);
        }

        // 5. commit prefetched slab to the other slot (after compute!)
        __builtin_amdgcn_sched_barrier(0);
        {
            float* wsl = &lds[((dz + 1) & 1) * SLAB];
            *(f4*)(wsl + r0 * RS + 4 + c0) = Ga;
            if (tid < 96)               *(f4*)(wsl + (4 + r0) * RS + 4 + c0) = Gb;
            if (tid >= 96 && tid < 108) wsl[rh * RS + ((tid & 1) ? 196 : 3)] = Gh;
        }
        __syncthreads();

        // 6. rotate plane registers (pure renaming under full unroll)
#pragma unroll
        for (int r = 0; r < 6; ++r) {
#pragma unroll
            for (int c = 0; c < 3; ++c) { P0[r][c] = P1[r][c]; P1[r][c] = P2[r][c]; }
        }
    }
}

extern "C" void kernel_launch(void* const* d_in, const int* in_sizes, int n_in,
                              void* d_out, int out_size, void* d_ws, size_t ws_size,
                              hipStream_t stream)
{
    const float* vol = (const float*)d_in[0];
    float* out       = (float*)d_out;

    const int B = in_sizes[0] / (Dd * Hh * Ww);   // = 2

    dim3 grid(Hh / NH, Dd / ZC, B);   // (48, 32, 2) = 3072 blocks, 12/CU
    dim3 block(Ww, 1, 1);             // 192 threads = 3 waves
    bilateral3d_v9<<<grid, block, 0, stream>>>(vol, out);
}